// Round 2
// baseline (57.714 us; speedup 1.0000x reference)
//
#include <hip/hip_runtime.h>

typedef float f32x4 __attribute__((ext_vector_type(4)));
typedef __bf16 bf16x8 __attribute__((ext_vector_type(8)));

#define K_FEAT 8192
#define N_FEAT 8192
#define M_TOK 64
#define TILES_N 512
#define TILES_K 512
#define WSTR 72   /* 64 k + 8 pad, in ushort units (144 B rows, 16B-aligned) */

__device__ __forceinline__ unsigned short f2bf(float f) {
    unsigned int u = __builtin_bit_cast(unsigned int, f);
    u = (u + 0x7FFFu + ((u >> 16) & 1u)) >> 16;
    return (unsigned short)u;
}

// xb[m][k] = bf16(x[m][k] * su[k])
__global__ void __launch_bounds__(256)
prep_x_kernel(const float* __restrict__ x, const float* __restrict__ su,
              unsigned short* __restrict__ xb)
{
    int i = blockIdx.x * 256 + threadIdx.x;          // float4 index over [64][8192]
    const float4* x4 = (const float4*)x;
    const float4* su4 = (const float4*)su;
    float4 xv = x4[i];
    float4 s4 = su4[i & (K_FEAT / 4 - 1)];
    ushort4 o;
    o.x = f2bf(xv.x * s4.x);
    o.y = f2bf(xv.y * s4.y);
    o.z = f2bf(xv.z * s4.z);
    o.w = f2bf(xv.w * s4.w);
    ((ushort4*)xb)[i] = o;
}

__global__ void __launch_bounds__(256)
trellis_main(const int* __restrict__ packed,
             const float* __restrict__ scales,
             const float* __restrict__ sv,
             const float* __restrict__ grid,
             const unsigned short* __restrict__ xb,
             float* __restrict__ partials,
             int lg_ksplit)
{
    __shared__ unsigned int table[256];
    __shared__ unsigned short wlds[2][32 * WSTR];

    const int tid = threadIdx.x;
    const int bid = blockIdx.x;
    const int ksplit = 1 << lg_ksplit;
    const int s = bid & (ksplit - 1);
    const int ng = bid >> lg_ksplit;                 // 0..255 (32-col groups)
    const int col0 = ng * 32;
    const int nt0 = ng * 2;
    const int ktile0 = s * (TILES_K >> lg_ksplit);
    const int nstep = (TILES_K >> lg_ksplit) >> 2;   // 4 k-tiles (64 rows) per step

    // ---- staging: 8 tiles/step = 4 kt x 2 nt; 32 threads per tile ----
    const int tau = tid >> 5;
    const int dkt = tau >> 1;        // 0..3
    const int dnt = tau & 1;         // 0..1
    const int w = tid & 31;
    const int c = w & 7;             // n-pair: rows 2c, 2c+1 (within n-tile)
    const int g = w >> 3;            // k-group: k = 4g..4g+3 (within k-tile)

    const int* pb = packed
        + ((size_t)(ktile0 + dkt) * TILES_N + (nt0 + dnt)) * 128 + c + 32 * g;
    const long stepstride = 4L * TILES_N * 128;      // advance 4 k-tiles

    // ---- compute coords ----
    const int wave = tid >> 6;       // m-tile 0..3
    const int lane = tid & 63;
    const int ln15 = lane & 15;
    const int kgrp = (lane >> 4) * 8;
    const unsigned short* xrow = xb + (size_t)(wave * 16 + ln15) * K_FEAT
                                    + ktile0 * 16 + kgrp;

    // pair table: byte -> (bf16(grid[lo]), bf16(grid[hi]))
    {
        float lo = grid[tid & 15];
        float hi = grid[(tid >> 4) & 15];
        table[tid] = (unsigned int)f2bf(lo) | ((unsigned int)f2bf(hi) << 16);
    }

    // prologue: depth-2 packed prefetch (sets A=step0, B=step1)
    int a0 = pb[0], a1 = pb[8], a2 = pb[16], a3 = pb[24];
    const int* p1 = pb + stepstride;
    int b0 = p1[0], b1 = p1[8], b2 = p1[16], b3 = p1[24];

    uint4 ra0 = *(const uint4*)(xrow);
    uint4 ra1 = *(const uint4*)(xrow + 32);

    f32x4 acc[2], acc2[2];
    for (int d = 0; d < 2; ++d)
        for (int j = 0; j < 4; ++j) { acc[d][j] = 0.f; acc2[d][j] = 0.f; }

    __syncthreads();   // table ready

    for (int t = 0; t < nstep; ++t) {
        // prefetch step t+2 (predicated: no wasted tail fetch)
        int c0, c1, c2, c3;
        if (t + 2 < nstep) {
            const int* pn = pb + stepstride * (t + 2);
            c0 = pn[0]; c1 = pn[8]; c2 = pn[16]; c3 = pn[24];
        } else { c0 = c1 = c2 = c3 = 0; }

        // dequant set A -> wlds[t&1], layout [n (32 rows)][k (64) + pad]
        unsigned int t0 = table[a0 & 255];
        unsigned int t1 = table[a1 & 255];
        unsigned int t2 = table[a2 & 255];
        unsigned int t3 = table[a3 & 255];
        unsigned int w0 = (t0 & 0xFFFFu) | (t1 << 16);          // n=2c,  k=4g,4g+1
        unsigned int w1 = (t2 & 0xFFFFu) | (t3 << 16);          // n=2c,  k=4g+2,4g+3
        unsigned int w2 = (t0 >> 16)     | (t1 & 0xFFFF0000u);  // n=2c+1
        unsigned int w3 = (t2 >> 16)     | (t3 & 0xFFFF0000u);
        {
            unsigned short* dst =
                &wlds[t & 1][(dnt * 16 + 2 * c) * WSTR + dkt * 16 + 4 * g];
            *(uint2*)dst = make_uint2(w0, w1);
            *(uint2*)(dst + WSTR) = make_uint2(w2, w3);
        }

        __syncthreads();   // one barrier/step (alternating buffers, validated r1)

        // prefetch next A-fragments (L2-resident xb)
        const unsigned short* xn = xrow + (t + 1 < nstep ? t + 1 : 0) * 64;
        uint4 rn0 = *(const uint4*)(xn);
        uint4 rn1 = *(const uint4*)(xn + 32);

        bf16x8 aa0 = __builtin_bit_cast(bf16x8, ra0);
        bf16x8 aa1 = __builtin_bit_cast(bf16x8, ra1);
        const unsigned short* wb = &wlds[t & 1][0];
        for (int d = 0; d < 2; ++d) {
            const unsigned short* br = wb + (d * 16 + ln15) * WSTR + kgrp;
            bf16x8 b0f = *(const bf16x8*)(br);
            acc2[d] = __builtin_amdgcn_mfma_f32_16x16x32_bf16(aa0, b0f, acc2[d], 0, 0, 0);
            bf16x8 b1f = *(const bf16x8*)(br + 32);
            acc2[d] = __builtin_amdgcn_mfma_f32_16x16x32_bf16(aa1, b1f, acc2[d], 0, 0, 0);
        }
        ra0 = rn0; ra1 = rn1;
        a0 = b0; a1 = b1; a2 = b2; a3 = b3;
        b0 = c0; b1 = c1; b2 = c2; b3 = c3;

        // every 2 steps (= 128 k rows = one scale block): fold scales into acc
        if (t & 1) {
            int kb = (ktile0 >> 3) + (t >> 1);
            const float* srow = scales + (size_t)kb * N_FEAT + col0 + ln15;
            for (int d = 0; d < 2; ++d) {
                float sc = srow[d * 16];
                acc[d] += acc2[d] * sc;
                for (int j = 0; j < 4; ++j) acc2[d][j] = 0.f;
            }
        }
    }

    // epilogue: apply sv, write partial [s][m][n]
    float* pout = partials + (size_t)s * (M_TOK * N_FEAT);
    const int rbase = (lane >> 4) * 4;
    for (int d = 0; d < 2; ++d) {
        int n = col0 + d * 16 + ln15;
        float svv = sv[n];
        for (int j = 0; j < 4; ++j) {
            int m = wave * 16 + rbase + j;
            pout[(size_t)m * N_FEAT + n] = acc[d][j] * svv;
        }
    }
}

__global__ void __launch_bounds__(256)
reduce_kernel(const float* __restrict__ partials, float* __restrict__ out, int ksplit)
{
    int i = blockIdx.x * 256 + threadIdx.x;          // float4 index, 131072 total
    const float4* p4 = (const float4*)partials;
    float4 a = p4[i];
    for (int k = 1; k < ksplit; ++k) {
        float4 v = p4[(size_t)k * (M_TOK * N_FEAT / 4) + i];
        a.x += v.x; a.y += v.y; a.z += v.z; a.w += v.w;
    }
    ((float4*)out)[i] = a;
}

extern "C" void kernel_launch(void* const* d_in, const int* in_sizes, int n_in,
                              void* d_out, int out_size, void* d_ws, size_t ws_size,
                              hipStream_t stream)
{
    const float* x      = (const float*)d_in[0];
    const int*   packed = (const int*)d_in[1];
    const float* scales = (const float*)d_in[2];
    const float* su     = (const float*)d_in[3];
    const float* sv     = (const float*)d_in[4];
    const float* grid   = (const float*)d_in[5];
    float* out = (float*)d_out;

    unsigned short* xb = (unsigned short*)d_ws;
    const size_t xb_bytes = (size_t)M_TOK * K_FEAT * 2;   // 1 MB
    int lg = 2;                                           // ksplit = 4
    while (lg > 0 &&
           xb_bytes + ((size_t)(1 << lg)) * M_TOK * N_FEAT * 4 > ws_size) --lg;
    const int ksplit = 1 << lg;
    float* partials = (float*)((char*)d_ws + xb_bytes);

    prep_x_kernel<<<(M_TOK * K_FEAT / 4) / 256, 256, 0, stream>>>(x, su, xb);
    trellis_main<<<(N_FEAT / 32) * ksplit, 256, 0, stream>>>(
        packed, scales, sv, grid, xb, partials, lg);
    reduce_kernel<<<(M_TOK * N_FEAT / 4) / 256, 256, 0, stream>>>(partials, out, ksplit);
}

// Round 3
// 38.037 us; speedup vs baseline: 1.5173x; 1.5173x over previous
//
#include <hip/hip_runtime.h>

typedef float f32x4 __attribute__((ext_vector_type(4)));
typedef __bf16 bf16x8 __attribute__((ext_vector_type(8)));

#define K_FEAT 8192
#define N_FEAT 8192
#define M_TOK 64
#define TILES_N 512
#define TILES_K 512
#define WROWSTRIDE 40   /* 32 k + 8 pad, in ushort units */
#define LG_KSPLIT 3
#define KSPLIT 8
#define NSTEP 32        /* (TILES_K/KSPLIT) tiles / 2 per step */

__device__ __forceinline__ unsigned short f2bf(float f) {
    unsigned int u = __builtin_bit_cast(unsigned int, f);
    u = (u + 0x7FFFu + ((u >> 16) & 1u)) >> 16;
    return (unsigned short)u;
}
__device__ __forceinline__ float bf2f(unsigned short h) {
    return __builtin_bit_cast(float, (unsigned int)h << 16);
}

// xb[m][k] = bf16(x[m][k] * su[k])
__global__ void __launch_bounds__(256)
prep_x_kernel(const float* __restrict__ x, const float* __restrict__ su,
              unsigned short* __restrict__ xb)
{
    int i = blockIdx.x * 256 + threadIdx.x;          // float4 index over [64][8192]
    const float4* x4 = (const float4*)x;
    const float4* su4 = (const float4*)su;
    float4 xv = x4[i];
    float4 s4 = su4[i & (K_FEAT / 4 - 1)];
    ushort4 o;
    o.x = f2bf(xv.x * s4.x);
    o.y = f2bf(xv.y * s4.y);
    o.z = f2bf(xv.z * s4.z);
    o.w = f2bf(xv.w * s4.w);
    ((ushort4*)xb)[i] = o;
}

__global__ void __launch_bounds__(256)
trellis_main(const int* __restrict__ packed,
             const float* __restrict__ scales,
             const float* __restrict__ sv,
             const float* __restrict__ grid,
             const unsigned short* __restrict__ xb,
             unsigned short* __restrict__ partials)
{
    __shared__ unsigned int table[256];
    __shared__ unsigned short wlds[2][64 * WROWSTRIDE];
    __shared__ float slds[8 * 64];   // 8 scale-blocks x 64 cols for this block

    const int tid = threadIdx.x;
    const int bid = blockIdx.x;
    const int s = bid & (KSPLIT - 1);
    const int ng = bid >> LG_KSPLIT;                 // 0..127 (64-col groups)
    const int col0 = ng * 64;
    const int nt0 = ng * 4;
    const int ktile0 = s * (TILES_K / KSPLIT);

    // ---- staging coords: 8 tiles/step = 2 kt x 4 nt; 32 threads per tile ----
    const int tau = tid >> 5;
    const int dkt = tau >> 2;        // 0..1
    const int dnt_s = tau & 3;       // 0..3
    const int w = tid & 31;
    const int c = w & 7;             // n-pair: rows 2c, 2c+1
    const int g = w >> 3;            // k-group: k = 4g..4g+3

    const int* pb = packed
        + ((size_t)(ktile0 + dkt) * TILES_N + (nt0 + dnt_s)) * 128 + c + 32 * g;
    const int stepstride = 2 * TILES_N * 128;        // advance 2 k-tiles

    // ---- compute coords ----
    const int wave = tid >> 6;       // m-tile 0..3
    const int lane = tid & 63;
    const int ln15 = lane & 15;
    const int kgrp = (lane >> 4) * 8;
    const unsigned short* xrow = xb + (size_t)(wave * 16 + ln15) * K_FEAT;

    // pair table: byte -> (bf16(grid[lo]), bf16(grid[hi]))
    {
        float lo = grid[tid & 15];
        float hi = grid[(tid >> 4) & 15];
        table[tid] = (unsigned int)f2bf(lo) | ((unsigned int)f2bf(hi) << 16);
    }
    // scales for this block's k-range: 8 blocks x 64 cols (keeps loop VMEM clean)
    {
        const int kb0 = s * 8;
        slds[tid]       = scales[(size_t)(kb0 + (tid >> 6)) * N_FEAT + col0 + (tid & 63)];
        slds[tid + 256] = scales[(size_t)(kb0 + 4 + (tid >> 6)) * N_FEAT + col0 + (tid & 63)];
    }

    // prologue: packed ints for step 0, A-frag for step 0
    int ld0 = pb[0], ld1 = pb[8], ld2 = pb[16], ld3 = pb[24];
    uint4 ra = *(const uint4*)(xrow + ktile0 * 16 + kgrp);

    f32x4 acc[4], acc2[4];
    for (int d = 0; d < 4; ++d)
        for (int j = 0; j < 4; ++j) { acc[d][j] = 0.f; acc2[d][j] = 0.f; }

    __syncthreads();   // table + slds ready (one full drain here is fine)

    for (int t = 0; t < NSTEP; ++t) {
        // prefetch next step's packed ints (stay in flight across the raw barrier)
        int n0 = 0, n1 = 0, n2 = 0, n3 = 0;
        if (t + 1 < NSTEP) {
            const int* pn = pb + (size_t)(t + 1) * stepstride;
            n0 = pn[0]; n1 = pn[8]; n2 = pn[16]; n3 = pn[24];
        }

        // dequant current step -> wlds[t&1], layout [n][k] (padded rows)
        unsigned int t0 = table[ld0 & 255];
        unsigned int t1 = table[ld1 & 255];
        unsigned int t2 = table[ld2 & 255];
        unsigned int t3 = table[ld3 & 255];
        unsigned int w0 = (t0 & 0xFFFFu) | (t1 << 16);          // row 2c,   k 4g..4g+1
        unsigned int w1 = (t2 & 0xFFFFu) | (t3 << 16);          // row 2c,   k 4g+2..4g+3
        unsigned int w2 = (t0 >> 16)     | (t1 & 0xFFFF0000u);  // row 2c+1
        unsigned int w3 = (t2 >> 16)     | (t3 & 0xFFFF0000u);
        {
            int nrow = dnt_s * 16 + 2 * c;
            int koff = dkt * 16 + 4 * g;
            unsigned short* dst = &wlds[t & 1][nrow * WROWSTRIDE + koff];
            *(uint2*)dst = make_uint2(w0, w1);
            *(uint2*)(dst + WROWSTRIDE) = make_uint2(w2, w3);
        }

        // raw barrier: wait only on LDS (lgkm), NOT on in-flight global loads.
        // __syncthreads would emit s_waitcnt vmcnt(0) and kill the prefetch.
        __builtin_amdgcn_sched_barrier(0);
        asm volatile("s_waitcnt lgkmcnt(0)" ::: "memory");
        __builtin_amdgcn_s_barrier();
        __builtin_amdgcn_sched_barrier(0);

        // prefetch next A-fragment (xb is L2-resident)
        int k0n = ktile0 * 16 + (t + 1 < NSTEP ? (t + 1) : 0) * 32;
        uint4 ran = *(const uint4*)(xrow + k0n + kgrp);

        bf16x8 a = __builtin_bit_cast(bf16x8, ra);
        const unsigned short* wbase = &wlds[t & 1][0];
        for (int d = 0; d < 4; ++d) {
            bf16x8 b = *(const bf16x8*)(wbase + (d * 16 + ln15) * WROWSTRIDE + kgrp);
            acc2[d] = __builtin_amdgcn_mfma_f32_16x16x32_bf16(a, b, acc2[d], 0, 0, 0);
        }
        ra = ran;
        ld0 = n0; ld1 = n1; ld2 = n2; ld3 = n3;

        // every 4 steps (= 128 k rows = one scale block): fold scales into acc
        if ((t & 3) == 3) {
            const float* srow = slds + (t >> 2) * 64 + ln15;
            for (int d = 0; d < 4; ++d) {
                float sc = srow[d * 16];
                acc[d] += acc2[d] * sc;
                for (int j = 0; j < 4; ++j) acc2[d][j] = 0.f;
            }
        }
    }

    // epilogue: apply sv, write bf16 partial [s][m][n]
    unsigned short* pout = partials + (size_t)s * (M_TOK * N_FEAT);
    const int rbase = (lane >> 4) * 4;
    for (int d = 0; d < 4; ++d) {
        int n = col0 + d * 16 + ln15;
        float svv = sv[n];
        for (int j = 0; j < 4; ++j) {
            int m = wave * 16 + rbase + j;
            pout[(size_t)m * N_FEAT + n] = f2bf(acc[d][j] * svv);
        }
    }
}

__global__ void __launch_bounds__(256)
reduce_kernel(const unsigned short* __restrict__ partials, float* __restrict__ out)
{
    int i = blockIdx.x * 256 + threadIdx.x;          // ushort8 group index (65536 total)
    const uint4* p = (const uint4*)partials;         // 8 bf16 per uint4
    float acc[8];
    for (int e = 0; e < 8; ++e) acc[e] = 0.f;
    for (int k = 0; k < KSPLIT; ++k) {
        uint4 v = p[(size_t)k * (M_TOK * N_FEAT / 8) + i];
        unsigned int uu[4] = {v.x, v.y, v.z, v.w};
        for (int q = 0; q < 4; ++q) {
            acc[2 * q]     += bf2f((unsigned short)(uu[q] & 0xFFFFu));
            acc[2 * q + 1] += bf2f((unsigned short)(uu[q] >> 16));
        }
    }
    float4 o0 = make_float4(acc[0], acc[1], acc[2], acc[3]);
    float4 o1 = make_float4(acc[4], acc[5], acc[6], acc[7]);
    ((float4*)out)[2 * i]     = o0;
    ((float4*)out)[2 * i + 1] = o1;
}

extern "C" void kernel_launch(void* const* d_in, const int* in_sizes, int n_in,
                              void* d_out, int out_size, void* d_ws, size_t ws_size,
                              hipStream_t stream)
{
    const float* x      = (const float*)d_in[0];
    const int*   packed = (const int*)d_in[1];
    const float* scales = (const float*)d_in[2];
    const float* su     = (const float*)d_in[3];
    const float* sv     = (const float*)d_in[4];
    const float* grid   = (const float*)d_in[5];
    float* out = (float*)d_out;

    unsigned short* xb = (unsigned short*)d_ws;
    const size_t xb_bytes = (size_t)M_TOK * K_FEAT * 2;   // 1 MB
    unsigned short* partials = (unsigned short*)((char*)d_ws + xb_bytes);

    prep_x_kernel<<<(M_TOK * K_FEAT / 4) / 256, 256, 0, stream>>>(x, su, xb);
    trellis_main<<<(N_FEAT / 64) * KSPLIT, 256, 0, stream>>>(
        packed, scales, sv, grid, xb, partials);
    reduce_kernel<<<(M_TOK * N_FEAT / 8) / 256, 256, 0, stream>>>(partials, out);
}